// Round 6
// baseline (269.469 us; speedup 1.0000x reference)
//
#include <hip/hip_runtime.h>
#include <math.h>

#define BB 8
#define SS 2048
#define EE 1024
#define HH 64
#define MM (BB * SS)   // 16384 rows

typedef unsigned short u16;
typedef __attribute__((ext_vector_type(8))) short short8;   // 8 x bf16
typedef __attribute__((ext_vector_type(4))) float floatx4;  // mfma C/D

__device__ __forceinline__ u16 f2bf(float f) {
    union { float f; unsigned u; } a; a.f = f;
    unsigned r = a.u + 0x7fffu + ((a.u >> 16) & 1u);   // RNE
    return (u16)(r >> 16);
}

// Split two fp32 into packed bf16 hi (truncated) and bf16 lo (residual, truncated).
// hi+lo reproduces fp32 to ~2^-16 relative.
__device__ __forceinline__ void split2(float f0, float f1, unsigned& hp, unsigned& lp) {
    union { float f; unsigned u; } a0, a1, h0, h1, l0, l1;
    a0.f = f0; a1.f = f1;
    h0.u = a0.u & 0xffff0000u;
    h1.u = a1.u & 0xffff0000u;
    l0.f = f0 - h0.f;
    l1.f = f1 - h1.f;
    hp = __builtin_amdgcn_perm(a1.u, a0.u, 0x07060302u);  // [hi16(f1)|hi16(f0)]
    lp = __builtin_amdgcn_perm(l1.u, l0.u, 0x07060302u);
}

// Async global->LDS, 16B per lane. lds base is wave-uniform; HW adds lane*16.
__device__ __forceinline__ void async_copy16(const u16* g, u16* l) {
    __builtin_amdgcn_global_load_lds(
        (const __attribute__((address_space(1))) unsigned*)g,
        (__attribute__((address_space(3))) unsigned*)l, 16, 0, 0);
}

// ---------------------------------------------------------------------------
// W pre-pack: fp32 W[1024][64] -> bf16 hi/lo fragments in exact MFMA B-frag
// order. Fragment f = t*8 + ks*4 + nt (t = 64-k chunk, ks = 32-k step,
// nt = 16-col tile). For lane l (n = l&15, g = l>>4) the fragment is the 8
// bf16 of W[t*64+ks*32+g*8 .. +7][nt*16+n].
// Layout (u16): Wp[matrix][ (f*2+hl)*512 + lane*8 ]  -> 256 KB per matrix.
// Wq (which==0) is pre-scaled by 0.125 (exact pow2 -> bit-identical flash
// scores), so flash_mfma needs no S scaling.
// ---------------------------------------------------------------------------
#define WP_MAT 131072   // u16 per matrix (128 frags * 2 hl * 512 shorts)

__global__ __launch_bounds__(512) void pack_w(
    const float* __restrict__ W0, const float* __restrict__ W1, const float* __restrict__ W2,
    u16* __restrict__ Wp)
{
    const int which = blockIdx.y;
    const float* __restrict__ W = (which == 0) ? W0 : (which == 1) ? W1 : W2;
    const float scale = (which == 0) ? 0.125f : 1.0f;   // exact pow2
    const int t    = blockIdx.x;           // k-chunk 0..15
    const int tid  = threadIdx.x;          // 0..511
    const int ks   = tid >> 8;
    const int nt   = (tid >> 6) & 3;
    const int lane = tid & 63;
    const int n    = lane & 15;
    const int g    = lane >> 4;

    const int k0 = t * 64 + ks * 32 + g * 8;
    const int c  = nt * 16 + n;

    float e[8];
    #pragma unroll
    for (int j = 0; j < 8; ++j) e[j] = W[(size_t)(k0 + j) * HH + c] * scale;

    unsigned hp[4], lp[4];
    #pragma unroll
    for (int i = 0; i < 4; ++i) split2(e[2 * i], e[2 * i + 1], hp[i], lp[i]);

    u16* dst = Wp + (size_t)which * WP_MAT
                  + ((size_t)(t * 8 + ks * 4 + nt) * 2) * 512 + lane * 8;
    *(uint4*)dst         = (uint4){hp[0], hp[1], hp[2], hp[3]};
    *(uint4*)(dst + 512) = (uint4){lp[0], lp[1], lp[2], lp[3]};
}

// ---------------------------------------------------------------------------
// Projection GEMM via bf16 MFMA + hi/lo compensation (3 passes).
// out[M x 64] = A[M x 1024] @ W[1024 x 64] + b.
// v7 = v6 + counted-vmcnt barriers (T3/T4): __syncthreads()'s vmcnt(0) drain
//     forced every chunk to wait full HBM latency of the A prefetch issued
//     mid-chunk. Now each chunk ends with s_waitcnt vmcnt(4) + raw s_barrier:
//     the 4 A loads (issued AFTER the W stage; order pinned by
//     sched_barrier(0)) stay in flight across the barrier; only the W stage
//     for the next buffer is guaranteed complete. Chunk 14 fully drains
//     (its newest vmem ops are W15's stage); chunk 15 needs no barrier.
//     Rule #20 discipline kept: named A slots, literal buffer indices.
// ---------------------------------------------------------------------------
#define PCH 16   // 64-k chunks

#define LOAD_A(AV, T)                                   \
    {                                                   \
        const float* p_ = ap + (T) * 64;                \
        AV[0] = *(const float4*)(p_ + 0);               \
        AV[1] = *(const float4*)(p_ + 4);               \
        AV[2] = *(const float4*)(p_ + 32);              \
        AV[3] = *(const float4*)(p_ + 36);              \
    }

// Counted barrier: W stage for next buffer complete; A prefetch (4 newest
// vmem ops) stays in flight. sched_barrier pins surrounding code.
#define VBAR4()                                                     \
    {                                                               \
        __builtin_amdgcn_sched_barrier(0);                          \
        asm volatile("s_waitcnt vmcnt(4)" ::: "memory");            \
        __builtin_amdgcn_s_barrier();                               \
        __builtin_amdgcn_sched_barrier(0);                          \
    }

// One 64-k chunk (no trailing barrier): stage W chunk TSTAGE into
// Wb[CURBUF^1] (vmem issue order pinned first), split AV (in regs),
// prefetch A chunk TPREF into AV, MFMA from Wb[CURBUF].
#define PROJ_CHUNK(AV, CURBUF, TSTAGE, TPREF)                                      \
    {                                                                              \
        if ((TSTAGE) < PCH) {                                                      \
            const u16* src_ = wpb + (size_t)(TSTAGE) * 8192 + wave * 2048 + lane * 8; \
            u16* dst_ = &Wb[(CURBUF) ^ 1][wave * 2048];                            \
            async_copy16(src_ + 0 * 512, dst_ + 0 * 512);                          \
            async_copy16(src_ + 1 * 512, dst_ + 1 * 512);                          \
            async_copy16(src_ + 2 * 512, dst_ + 2 * 512);                          \
            async_copy16(src_ + 3 * 512, dst_ + 3 * 512);                          \
        }                                                                          \
        __builtin_amdgcn_sched_barrier(0);                                         \
        short8 ah0, ah1, al0, al1;                                                 \
        {                                                                          \
            unsigned hp0, lp0, hp1, lp1, hp2, lp2, hp3, lp3;                       \
            split2(AV[0].x, AV[0].y, hp0, lp0);                                    \
            split2(AV[0].z, AV[0].w, hp1, lp1);                                    \
            split2(AV[1].x, AV[1].y, hp2, lp2);                                    \
            split2(AV[1].z, AV[1].w, hp3, lp3);                                    \
            union { uint4 u; short8 s; } ch_, cl_;                                 \
            ch_.u = (uint4){hp0, hp1, hp2, hp3};                                   \
            cl_.u = (uint4){lp0, lp1, lp2, lp3};                                   \
            ah0 = ch_.s; al0 = cl_.s;                                              \
            split2(AV[2].x, AV[2].y, hp0, lp0);                                    \
            split2(AV[2].z, AV[2].w, hp1, lp1);                                    \
            split2(AV[3].x, AV[3].y, hp2, lp2);                                    \
            split2(AV[3].z, AV[3].w, hp3, lp3);                                    \
            ch_.u = (uint4){hp0, hp1, hp2, hp3};                                   \
            cl_.u = (uint4){lp0, lp1, lp2, lp3};                                   \
            ah1 = ch_.s; al1 = cl_.s;                                              \
        }                                                                          \
        if ((TPREF) < PCH) LOAD_A(AV, TPREF);                                      \
        _Pragma("unroll")                                                          \
        for (int nt = 0; nt < 4; ++nt) {                                           \
            const short8 whf = *(const short8*)&Wb[CURBUF][nt * 1024 + lane * 8];  \
            const short8 wlf = *(const short8*)&Wb[CURBUF][nt * 1024 + 512 + lane * 8]; \
            acc[nt] = __builtin_amdgcn_mfma_f32_16x16x32_bf16(ah0, whf, acc[nt], 0, 0, 0); \
            acc[nt] = __builtin_amdgcn_mfma_f32_16x16x32_bf16(al0, whf, acc[nt], 0, 0, 0); \
            acc[nt] = __builtin_amdgcn_mfma_f32_16x16x32_bf16(ah0, wlf, acc[nt], 0, 0, 0); \
        }                                                                          \
        _Pragma("unroll")                                                          \
        for (int nt = 0; nt < 4; ++nt) {                                           \
            const short8 whf = *(const short8*)&Wb[CURBUF][4096 + nt * 1024 + lane * 8]; \
            const short8 wlf = *(const short8*)&Wb[CURBUF][4096 + nt * 1024 + 512 + lane * 8]; \
            acc[nt] = __builtin_amdgcn_mfma_f32_16x16x32_bf16(ah1, whf, acc[nt], 0, 0, 0); \
            acc[nt] = __builtin_amdgcn_mfma_f32_16x16x32_bf16(al1, whf, acc[nt], 0, 0, 0); \
            acc[nt] = __builtin_amdgcn_mfma_f32_16x16x32_bf16(ah1, wlf, acc[nt], 0, 0, 0); \
        }                                                                          \
    }

__global__ __launch_bounds__(256) void proj_mfma(
    const float* __restrict__ A0, const float* __restrict__ A1, const float* __restrict__ A2,
    const u16* __restrict__ Wp,
    const float* __restrict__ b0, const float* __restrict__ b1, const float* __restrict__ b2,
    u16* __restrict__ o0, u16* __restrict__ o1, u16* __restrict__ o2)
{
    const int which = blockIdx.y;
    const float* __restrict__ A    = (which == 0) ? A0 : (which == 1) ? A1 : A2;
    const float* __restrict__ bias = (which == 0) ? b0 : (which == 1) ? b1 : b2;
    u16* __restrict__ out          = (which == 0) ? o0 : (which == 1) ? o1 : o2;
    const float bscale = (which == 0) ? 0.125f : 1.0f;

    __shared__ __align__(16) u16 Wb[2][8192];   // 16 KB per buffer

    const int tid  = threadIdx.x;
    const int lane = tid & 63;
    const int wave = tid >> 6;
    const int n    = lane & 15;
    const int g    = lane >> 4;
    const int row0 = blockIdx.x * 64;

    // A fragment source: row (row0 + wave*16 + n), 8 contiguous floats at g*8
    const float* __restrict__ ap = A + (size_t)(row0 + wave * 16 + n) * EE + g * 8;
    // W packed source for this matrix
    const u16* __restrict__ wpb = Wp + (size_t)which * WP_MAT;

    floatx4 acc[4];
    #pragma unroll
    for (int nt = 0; nt < 4; ++nt) acc[nt] = (floatx4){0.f, 0.f, 0.f, 0.f};

    // ---- prologue: A chunks 0,1 -> named reg slots; W chunk 0 -> LDS buf 0
    float4 avA[4], avB[4];   // [ks*2 + half]: ks*32 + g*8 (+4)
    LOAD_A(avA, 0);
    LOAD_A(avB, 1);
    {
        const u16* src = wpb + wave * 2048 + lane * 8;
        u16* dst = &Wb[0][wave * 2048];
        #pragma unroll
        for (int i = 0; i < 4; ++i)
            async_copy16(src + i * 512, dst + i * 512);
    }
    __syncthreads();

    // ---- main loop: chunks 0..11, counted-vmcnt barriers ------------------
    for (int tt = 0; tt < 12; tt += 2) {
        PROJ_CHUNK(avA, 0, tt + 1, tt + 2);   // compute chunk tt   from Wb[0]
        VBAR4();
        PROJ_CHUNK(avB, 1, tt + 2, tt + 3);   // compute chunk tt+1 from Wb[1]
        VBAR4();
    }
    // ---- peeled tail: chunks 12..15 ---------------------------------------
    PROJ_CHUNK(avA, 0, 13, 14);  VBAR4();
    PROJ_CHUNK(avB, 1, 14, 15);  VBAR4();
    PROJ_CHUNK(avA, 0, 15, 16);  __syncthreads();   // newest vmem = W15: full drain
    PROJ_CHUNK(avB, 1, 16, 17);                      // last chunk: no barrier

    // ---- epilogue: bias + bf16 store -------------------------------------
    #pragma unroll
    for (int nt = 0; nt < 4; ++nt) {
        const float bv = bias[nt * 16 + n] * bscale;
        #pragma unroll
        for (int r = 0; r < 4; ++r) {
            const int row = row0 + wave * 16 + g * 4 + r;
            out[(size_t)row * HH + nt * 16 + n] = f2bf(acc[nt][r] + bv);
        }
    }
}

// ---------------------------------------------------------------------------
// MFMA flash attention, double-buffered 64-key tiles, 1 barrier/iter.
// Block 256 thr = 4 waves: wq = wave&1 (16-q tile), ks = wave>>1 (32-key half).
// Grid (64, 8). Next tile loaded to regs before compute, written after.
// NOTE: qp is pre-scaled by 0.125 (folded into Wq/bq), so no S scaling here.
// ---------------------------------------------------------------------------
__global__ __launch_bounds__(256) void flash_mfma(
    const u16* __restrict__ qp, const u16* __restrict__ kp,
    const u16* __restrict__ vp, float* __restrict__ out)
{
    __shared__ __align__(16) u16 Ks[2][64 * 64];   // row j: 8 chunks, chunk cs at cs^(j&7)
    __shared__ __align__(16) u16 Vt[2][64 * 64];   // row h: 8 j-chunks, chunk cj at cj^(h&7)
    __shared__ __align__(16) u16 Pw[4][16 * 72];

    const int b    = blockIdx.y;
    const int q0   = blockIdx.x * 32;
    const int tid  = threadIdx.x;
    const int lane = tid & 63;
    const int wave = tid >> 6;
    const int wq   = wave & 1;
    const int ks   = wave >> 1;
    const int n    = lane & 15;
    const int g    = lane >> 4;

    const u16* qrow = qp + ((size_t)b * SS + q0 + wq * 16 + n) * HH;
    const short8 qa0 = *(const short8*)(qrow + g * 8);
    const short8 qa1 = *(const short8*)(qrow + 32 + g * 8);

    floatx4 Oa[4];
    #pragma unroll
    for (int ht = 0; ht < 4; ++ht) Oa[ht] = (floatx4){0.f, 0.f, 0.f, 0.f};
    float m_i[4], l_i[4];
    #pragma unroll
    for (int r = 0; r < 4; ++r) { m_i[r] = -1e30f; l_i[r] = 0.f; }

    const u16* kb = kp + (size_t)b * SS * HH;
    const u16* vb = vp + (size_t)b * SS * HH;

    // staging indices (tid-only)
    const int jK0 = tid >> 3, jK1 = 32 + (tid >> 3), cs = tid & 7;
    const int jV  = (tid & 15) * 4, hV = (tid >> 4) * 4;

    short8  kr0, kr1;
    ushort4 vr0, vr1, vr2, vr3;

    // ---- prologue: stage tile 0 into buf 0 --------------------------------
    kr0 = *(const short8*)(kb + (size_t)jK0 * HH + cs * 8);
    kr1 = *(const short8*)(kb + (size_t)jK1 * HH + cs * 8);
    vr0 = *(const ushort4*)(vb + (size_t)(jV + 0) * HH + hV);
    vr1 = *(const ushort4*)(vb + (size_t)(jV + 1) * HH + hV);
    vr2 = *(const ushort4*)(vb + (size_t)(jV + 2) * HH + hV);
    vr3 = *(const ushort4*)(vb + (size_t)(jV + 3) * HH + hV);
    {
        *(short8*)&Ks[0][jK0 * 64 + ((cs ^ (jK0 & 7)) << 3)] = kr0;
        *(short8*)&Ks[0][jK1 * 64 + ((cs ^ (jK1 & 7)) << 3)] = kr1;
        const u16* a0 = (const u16*)&vr0; const u16* a1 = (const u16*)&vr1;
        const u16* a2 = (const u16*)&vr2; const u16* a3 = (const u16*)&vr3;
        #pragma unroll
        for (int i = 0; i < 4; ++i) {
            const int h = hV + i;
            ushort4 w; w.x = a0[i]; w.y = a1[i]; w.z = a2[i]; w.w = a3[i];
            *(ushort4*)((char*)&Vt[0][0] + h * 128 + (((jV >> 3) ^ (h & 7)) << 4) + ((jV & 4) << 1)) = w;
        }
    }
    __syncthreads();

    for (int t = 0; t < SS / 64; ++t) {
        const int cur = t & 1;

        // ---- issue next tile's global loads (latency hides under compute) --
        if (t + 1 < SS / 64) {
            const size_t kt = (size_t)(t + 1) * 64;
            kr0 = *(const short8*)(kb + (kt + jK0) * HH + cs * 8);
            kr1 = *(const short8*)(kb + (kt + jK1) * HH + cs * 8);
            vr0 = *(const ushort4*)(vb + (kt + jV + 0) * HH + hV);
            vr1 = *(const ushort4*)(vb + (kt + jV + 1) * HH + hV);
            vr2 = *(const ushort4*)(vb + (kt + jV + 2) * HH + hV);
            vr3 = *(const ushort4*)(vb + (kt + jV + 3) * HH + hV);
        }

        // ---- QK^T: S[16 q][32 keys] (my half) ------------------------------
        floatx4 S[2];
        #pragma unroll
        for (int nt = 0; nt < 2; ++nt) {
            const int j = ks * 32 + nt * 16 + n;
            const short8 kf0 = *(const short8*)&Ks[cur][j * 64 + (((0 + g) ^ (j & 7)) << 3)];
            const short8 kf1 = *(const short8*)&Ks[cur][j * 64 + (((4 + g) ^ (j & 7)) << 3)];
            floatx4 a = (floatx4){0.f, 0.f, 0.f, 0.f};
            a = __builtin_amdgcn_mfma_f32_16x16x32_bf16(qa0, kf0, a, 0, 0, 0);
            a = __builtin_amdgcn_mfma_f32_16x16x32_bf16(qa1, kf1, a, 0, 0, 0);
            S[nt] = a;
        }

        // ---- online softmax ------------------------------------------------
        float mx[4];
        #pragma unroll
        for (int r = 0; r < 4; ++r) mx[r] = -1e30f;
        #pragma unroll
        for (int nt = 0; nt < 2; ++nt)
            #pragma unroll
            for (int r = 0; r < 4; ++r)
                mx[r] = fmaxf(mx[r], S[nt][r]);
        #pragma unroll
        for (int off = 8; off >= 1; off >>= 1)
            #pragma unroll
            for (int r = 0; r < 4; ++r)
                mx[r] = fmaxf(mx[r], __shfl_xor(mx[r], off, 64));

        float alpha[4], ps[4];
        #pragma unroll
        for (int r = 0; r < 4; ++r) {
            const float Mn = fmaxf(m_i[r], mx[r]);
            alpha[r] = __expf(m_i[r] - Mn);
            m_i[r]   = Mn;
            ps[r]    = 0.f;
        }
        float p[2][4];
        #pragma unroll
        for (int nt = 0; nt < 2; ++nt)
            #pragma unroll
            for (int r = 0; r < 4; ++r) {
                p[nt][r] = __expf(S[nt][r] - m_i[r]);
                ps[r] += p[nt][r];
            }
        #pragma unroll
        for (int off = 8; off >= 1; off >>= 1)
            #pragma unroll
            for (int r = 0; r < 4; ++r)
                ps[r] += __shfl_xor(ps[r], off, 64);
        #pragma unroll
        for (int r = 0; r < 4; ++r) l_i[r] = l_i[r] * alpha[r] + ps[r];
        #pragma unroll
        for (int ht = 0; ht < 4; ++ht)
            #pragma unroll
            for (int r = 0; r < 4; ++r) Oa[ht][r] *= alpha[r];

        // ---- P: C-layout -> LDS -> A-layout (per-wave, no barrier needed) --
        #pragma unroll
        for (int nt = 0; nt < 2; ++nt)
            #pragma unroll
            for (int r = 0; r < 4; ++r)
                Pw[wave][(g * 4 + r) * 72 + nt * 16 + n] = f2bf(p[nt][r]);
        const short8 pa = *(const short8*)&Pw[wave][n * 72 + g * 8];

        // ---- PV: O[16 q][64 h] += P[16 x 32] @ V[32 x 64] ------------------
        #pragma unroll
        for (int ht = 0; ht < 4; ++ht) {
            const int h = ht * 16 + n;
            const short8 vf = *(const short8*)((const char*)&Vt[cur][0] + h * 128 +
                                               ((((ks << 2) + g) ^ (h & 7)) << 4));
            Oa[ht] = __builtin_amdgcn_mfma_f32_16x16x32_bf16(pa, vf, Oa[ht], 0, 0, 0);
        }

        // ---- write next tile into the other buffer -------------------------
        if (t + 1 < SS / 64) {
            const int nx = cur ^ 1;
            *(short8*)&Ks[nx][jK0 * 64 + ((cs ^ (jK0 & 7)) << 3)] = kr0;
            *(short8*)&Ks[nx][jK1 * 64 + ((cs ^ (jK1 & 7)) << 3)] = kr1;
            const u16* a0 = (const u16*)&vr0; const u16* a1 = (const u16*)&vr1;
            const u16* a2 = (const u16*)&vr2; const u16* a3 = (const u16*)&vr3;
            #pragma unroll
            for (int i = 0; i < 4; ++i) {
                const int h = hV + i;
                ushort4 w; w.x = a0[i]; w.y = a1[i]; w.z = a2[i]; w.w = a3[i];
                *(ushort4*)((char*)&Vt[nx][0] + h * 128 + (((jV >> 3) ^ (h & 7)) << 4) + ((jV & 4) << 1)) = w;
            }
        }
        __syncthreads();
    }

    // ---- combine the two key-splits via LDS (reuse Ks) ----------------------
    float* Cb = (float*)&Ks[0][0];          // [wq][16][68]
    float* Cm = Cb + 2 * 16 * 68;           // [wq][16]
    float* Cl = Cm + 32;
    if (ks == 1) {
        #pragma unroll
        for (int ht = 0; ht < 4; ++ht)
            #pragma unroll
            for (int r = 0; r < 4; ++r)
                Cb[(wq * 16 + g * 4 + r) * 68 + ht * 16 + n] = Oa[ht][r];
        if (n == 0)
            #pragma unroll
            for (int r = 0; r < 4; ++r) {
                Cm[wq * 16 + g * 4 + r] = m_i[r];
                Cl[wq * 16 + g * 4 + r] = l_i[r];
            }
    }
    __syncthreads();
    if (ks == 0) {
        float a0v[4], a1v[4], linv[4];
        #pragma unroll
        for (int r = 0; r < 4; ++r) {
            const int m = g * 4 + r;
            const float m1 = Cm[wq * 16 + m], l1 = Cl[wq * 16 + m];
            const float M  = fmaxf(m_i[r], m1);
            const float e0 = __expf(m_i[r] - M), e1 = __expf(m1 - M);
            a0v[r] = e0; a1v[r] = e1;
            linv[r] = 1.f / (l_i[r] * e0 + l1 * e1);
        }
        #pragma unroll
        for (int ht = 0; ht < 4; ++ht)
            #pragma unroll
            for (int r = 0; r < 4; ++r) {
                const float o1 = Cb[(wq * 16 + g * 4 + r) * 68 + ht * 16 + n];
                const float v  = (Oa[ht][r] * a0v[r] + o1 * a1v[r]) * linv[r];
                out[((size_t)b * SS + q0 + wq * 16 + g * 4 + r) * HH + ht * 16 + n] = v;
            }
    }
}

// ---------------------------------------------------------------------------
extern "C" void kernel_launch(void* const* d_in, const int* in_sizes, int n_in,
                              void* d_out, int out_size, void* d_ws, size_t ws_size,
                              hipStream_t stream) {
    const float* query = (const float*)d_in[0];
    const float* key   = (const float*)d_in[1];
    const float* value = (const float*)d_in[2];
    const float* Wq    = (const float*)d_in[3];
    const float* bq    = (const float*)d_in[4];
    const float* Wk    = (const float*)d_in[5];
    const float* bk    = (const float*)d_in[6];
    const float* Wv    = (const float*)d_in[7];
    const float* bv    = (const float*)d_in[8];
    float* out = (float*)d_out;

    u16* qp = (u16*)d_ws;                        // 16384 x 64 bf16 each
    u16* kp = qp + (size_t)MM * HH;
    u16* vp = kp + (size_t)MM * HH;
    u16* Wp = vp + (size_t)MM * HH;              // 3 * 256 KB packed W frags

    dim3 wgrid(EE / 64, 3);
    pack_w<<<wgrid, 512, 0, stream>>>(Wq, Wk, Wv, Wp);

    dim3 pgrid(MM / 64, 3);
    proj_mfma<<<pgrid, 256, 0, stream>>>(query, key, value,
                                         Wp,
                                         bq, bk, bv,
                                         qp, kp, vp);

    dim3 agrid(SS / 32, BB);
    flash_mfma<<<agrid, 256, 0, stream>>>(qp, kp, vp, out);
}

// Round 7
// 260.013 us; speedup vs baseline: 1.0364x; 1.0364x over previous
//
#include <hip/hip_runtime.h>
#include <math.h>

#define BB 8
#define SS 2048
#define EE 1024
#define HH 64
#define MM (BB * SS)   // 16384 rows

typedef unsigned short u16;
typedef __attribute__((ext_vector_type(8))) short short8;   // 8 x bf16
typedef __attribute__((ext_vector_type(4))) float floatx4;  // mfma C/D

__device__ __forceinline__ u16 f2bf(float f) {
    union { float f; unsigned u; } a; a.f = f;
    unsigned r = a.u + 0x7fffu + ((a.u >> 16) & 1u);   // RNE
    return (u16)(r >> 16);
}

// Split two fp32 into packed bf16 hi (truncated) and bf16 lo (residual, truncated).
// hi+lo reproduces fp32 to ~2^-16 relative.
__device__ __forceinline__ void split2(float f0, float f1, unsigned& hp, unsigned& lp) {
    union { float f; unsigned u; } a0, a1, h0, h1, l0, l1;
    a0.f = f0; a1.f = f1;
    h0.u = a0.u & 0xffff0000u;
    h1.u = a1.u & 0xffff0000u;
    l0.f = f0 - h0.f;
    l1.f = f1 - h1.f;
    hp = __builtin_amdgcn_perm(a1.u, a0.u, 0x07060302u);  // [hi16(f1)|hi16(f0)]
    lp = __builtin_amdgcn_perm(l1.u, l0.u, 0x07060302u);
}

// Async global->LDS, 16B per lane. lds base is wave-uniform; HW adds lane*16.
__device__ __forceinline__ void async_copy16(const u16* g, u16* l) {
    __builtin_amdgcn_global_load_lds(
        (const __attribute__((address_space(1))) unsigned*)g,
        (__attribute__((address_space(3))) unsigned*)l, 16, 0, 0);
}

// ---- DPP 16-lane butterfly reductions (VALU pipe, no LDS traffic) ----------
// Levels: quad_perm xor1 (0xB1), quad_perm xor2 (0x4E), row_half_mirror
// (0x141), row_mirror (0x140). Valid reduction network for commutative ops
// over each aligned 16-lane group; all lanes end with the result.
template <int CTRL>
__device__ __forceinline__ float dppf(float x) {
    union { float f; int i; } a, b;
    a.f = x;
    b.i = __builtin_amdgcn_update_dpp(a.i, a.i, CTRL, 0xF, 0xF, true);
    return b.f;
}
__device__ __forceinline__ float red_max16(float x) {
    x = fmaxf(x, dppf<0xB1>(x));
    x = fmaxf(x, dppf<0x4E>(x));
    x = fmaxf(x, dppf<0x141>(x));
    x = fmaxf(x, dppf<0x140>(x));
    return x;
}
__device__ __forceinline__ float red_sum16(float x) {
    x += dppf<0xB1>(x);
    x += dppf<0x4E>(x);
    x += dppf<0x141>(x);
    x += dppf<0x140>(x);
    return x;
}

// ---------------------------------------------------------------------------
// W pre-pack: fp32 W[1024][64] -> bf16 hi/lo fragments in exact MFMA B-frag
// order. Fragment f = t*8 + ks*4 + nt (t = 64-k chunk, ks = 32-k step,
// nt = 16-col tile). For lane l (n = l&15, g = l>>4) the fragment is the 8
// bf16 of W[t*64+ks*32+g*8 .. +7][nt*16+n].
// Layout (u16): Wp[matrix][ (f*2+hl)*512 + lane*8 ]  -> 256 KB per matrix.
// Wq (which==0) is pre-scaled by 0.125 (exact pow2 -> bit-identical flash
// scores), so flash_mfma needs no S scaling.
// ---------------------------------------------------------------------------
#define WP_MAT 131072   // u16 per matrix (128 frags * 2 hl * 512 shorts)

__global__ __launch_bounds__(512) void pack_w(
    const float* __restrict__ W0, const float* __restrict__ W1, const float* __restrict__ W2,
    u16* __restrict__ Wp)
{
    const int which = blockIdx.y;
    const float* __restrict__ W = (which == 0) ? W0 : (which == 1) ? W1 : W2;
    const float scale = (which == 0) ? 0.125f : 1.0f;   // exact pow2
    const int t    = blockIdx.x;           // k-chunk 0..15
    const int tid  = threadIdx.x;          // 0..511
    const int ks   = tid >> 8;
    const int nt   = (tid >> 6) & 3;
    const int lane = tid & 63;
    const int n    = lane & 15;
    const int g    = lane >> 4;

    const int k0 = t * 64 + ks * 32 + g * 8;
    const int c  = nt * 16 + n;

    float e[8];
    #pragma unroll
    for (int j = 0; j < 8; ++j) e[j] = W[(size_t)(k0 + j) * HH + c] * scale;

    unsigned hp[4], lp[4];
    #pragma unroll
    for (int i = 0; i < 4; ++i) split2(e[2 * i], e[2 * i + 1], hp[i], lp[i]);

    u16* dst = Wp + (size_t)which * WP_MAT
                  + ((size_t)(t * 8 + ks * 4 + nt) * 2) * 512 + lane * 8;
    *(uint4*)dst         = (uint4){hp[0], hp[1], hp[2], hp[3]};
    *(uint4*)(dst + 512) = (uint4){lp[0], lp[1], lp[2], lp[3]};
}

// ---------------------------------------------------------------------------
// Projection GEMM via bf16 MFMA + hi/lo compensation (3 passes).
// out[M x 64] = A[M x 1024] @ W[1024 x 64] + b.
// v7 structure kept (counted-vmcnt barriers; R6 showed parity with plain
// __syncthreads, so the barrier is not the proj bottleneck — left as-is).
// ---------------------------------------------------------------------------
#define PCH 16   // 64-k chunks

#define LOAD_A(AV, T)                                   \
    {                                                   \
        const float* p_ = ap + (T) * 64;                \
        AV[0] = *(const float4*)(p_ + 0);               \
        AV[1] = *(const float4*)(p_ + 4);               \
        AV[2] = *(const float4*)(p_ + 32);              \
        AV[3] = *(const float4*)(p_ + 36);              \
    }

#define VBAR4()                                                     \
    {                                                               \
        __builtin_amdgcn_sched_barrier(0);                          \
        asm volatile("s_waitcnt vmcnt(4)" ::: "memory");            \
        __builtin_amdgcn_s_barrier();                               \
        __builtin_amdgcn_sched_barrier(0);                          \
    }

#define PROJ_CHUNK(AV, CURBUF, TSTAGE, TPREF)                                      \
    {                                                                              \
        if ((TSTAGE) < PCH) {                                                      \
            const u16* src_ = wpb + (size_t)(TSTAGE) * 8192 + wave * 2048 + lane * 8; \
            u16* dst_ = &Wb[(CURBUF) ^ 1][wave * 2048];                            \
            async_copy16(src_ + 0 * 512, dst_ + 0 * 512);                          \
            async_copy16(src_ + 1 * 512, dst_ + 1 * 512);                          \
            async_copy16(src_ + 2 * 512, dst_ + 2 * 512);                          \
            async_copy16(src_ + 3 * 512, dst_ + 3 * 512);                          \
        }                                                                          \
        __builtin_amdgcn_sched_barrier(0);                                         \
        short8 ah0, ah1, al0, al1;                                                 \
        {                                                                          \
            unsigned hp0, lp0, hp1, lp1, hp2, lp2, hp3, lp3;                       \
            split2(AV[0].x, AV[0].y, hp0, lp0);                                    \
            split2(AV[0].z, AV[0].w, hp1, lp1);                                    \
            split2(AV[1].x, AV[1].y, hp2, lp2);                                    \
            split2(AV[1].z, AV[1].w, hp3, lp3);                                    \
            union { uint4 u; short8 s; } ch_, cl_;                                 \
            ch_.u = (uint4){hp0, hp1, hp2, hp3};                                   \
            cl_.u = (uint4){lp0, lp1, lp2, lp3};                                   \
            ah0 = ch_.s; al0 = cl_.s;                                              \
            split2(AV[2].x, AV[2].y, hp0, lp0);                                    \
            split2(AV[2].z, AV[2].w, hp1, lp1);                                    \
            split2(AV[3].x, AV[3].y, hp2, lp2);                                    \
            split2(AV[3].z, AV[3].w, hp3, lp3);                                    \
            ch_.u = (uint4){hp0, hp1, hp2, hp3};                                   \
            cl_.u = (uint4){lp0, lp1, lp2, lp3};                                   \
            ah1 = ch_.s; al1 = cl_.s;                                              \
        }                                                                          \
        if ((TPREF) < PCH) LOAD_A(AV, TPREF);                                      \
        _Pragma("unroll")                                                          \
        for (int nt = 0; nt < 4; ++nt) {                                           \
            const short8 whf = *(const short8*)&Wb[CURBUF][nt * 1024 + lane * 8];  \
            const short8 wlf = *(const short8*)&Wb[CURBUF][nt * 1024 + 512 + lane * 8]; \
            acc[nt] = __builtin_amdgcn_mfma_f32_16x16x32_bf16(ah0, whf, acc[nt], 0, 0, 0); \
            acc[nt] = __builtin_amdgcn_mfma_f32_16x16x32_bf16(al0, whf, acc[nt], 0, 0, 0); \
            acc[nt] = __builtin_amdgcn_mfma_f32_16x16x32_bf16(ah0, wlf, acc[nt], 0, 0, 0); \
        }                                                                          \
        _Pragma("unroll")                                                          \
        for (int nt = 0; nt < 4; ++nt) {                                           \
            const short8 whf = *(const short8*)&Wb[CURBUF][4096 + nt * 1024 + lane * 8]; \
            const short8 wlf = *(const short8*)&Wb[CURBUF][4096 + nt * 1024 + 512 + lane * 8]; \
            acc[nt] = __builtin_amdgcn_mfma_f32_16x16x32_bf16(ah1, whf, acc[nt], 0, 0, 0); \
            acc[nt] = __builtin_amdgcn_mfma_f32_16x16x32_bf16(al1, whf, acc[nt], 0, 0, 0); \
            acc[nt] = __builtin_amdgcn_mfma_f32_16x16x32_bf16(ah1, wlf, acc[nt], 0, 0, 0); \
        }                                                                          \
    }

__global__ __launch_bounds__(256) void proj_mfma(
    const float* __restrict__ A0, const float* __restrict__ A1, const float* __restrict__ A2,
    const u16* __restrict__ Wp,
    const float* __restrict__ b0, const float* __restrict__ b1, const float* __restrict__ b2,
    u16* __restrict__ o0, u16* __restrict__ o1, u16* __restrict__ o2)
{
    const int which = blockIdx.y;
    const float* __restrict__ A    = (which == 0) ? A0 : (which == 1) ? A1 : A2;
    const float* __restrict__ bias = (which == 0) ? b0 : (which == 1) ? b1 : b2;
    u16* __restrict__ out          = (which == 0) ? o0 : (which == 1) ? o1 : o2;
    const float bscale = (which == 0) ? 0.125f : 1.0f;

    __shared__ __align__(16) u16 Wb[2][8192];   // 16 KB per buffer

    const int tid  = threadIdx.x;
    const int lane = tid & 63;
    const int wave = tid >> 6;
    const int n    = lane & 15;
    const int g    = lane >> 4;
    const int row0 = blockIdx.x * 64;

    const float* __restrict__ ap = A + (size_t)(row0 + wave * 16 + n) * EE + g * 8;
    const u16* __restrict__ wpb = Wp + (size_t)which * WP_MAT;

    floatx4 acc[4];
    #pragma unroll
    for (int nt = 0; nt < 4; ++nt) acc[nt] = (floatx4){0.f, 0.f, 0.f, 0.f};

    float4 avA[4], avB[4];   // [ks*2 + half]: ks*32 + g*8 (+4)
    LOAD_A(avA, 0);
    LOAD_A(avB, 1);
    {
        const u16* src = wpb + wave * 2048 + lane * 8;
        u16* dst = &Wb[0][wave * 2048];
        #pragma unroll
        for (int i = 0; i < 4; ++i)
            async_copy16(src + i * 512, dst + i * 512);
    }
    __syncthreads();

    for (int tt = 0; tt < 12; tt += 2) {
        PROJ_CHUNK(avA, 0, tt + 1, tt + 2);
        VBAR4();
        PROJ_CHUNK(avB, 1, tt + 2, tt + 3);
        VBAR4();
    }
    PROJ_CHUNK(avA, 0, 13, 14);  VBAR4();
    PROJ_CHUNK(avB, 1, 14, 15);  VBAR4();
    PROJ_CHUNK(avA, 0, 15, 16);  __syncthreads();
    PROJ_CHUNK(avB, 1, 16, 17);

    #pragma unroll
    for (int nt = 0; nt < 4; ++nt) {
        const float bv = bias[nt * 16 + n] * bscale;
        #pragma unroll
        for (int r = 0; r < 4; ++r) {
            const int row = row0 + wave * 16 + g * 4 + r;
            out[(size_t)row * HH + nt * 16 + n] = f2bf(acc[nt][r] + bv);
        }
    }
}

// ---------------------------------------------------------------------------
// MFMA flash attention, double-buffered 64-key tiles, 1 barrier/iter.
// Block 256 thr = 4 waves: wq = wave&1 (16-q tile), ks = wave>>1 (32-key half).
// Grid (64, 8). Next tile loaded to regs before compute, written after.
// v2: cross-lane softmax reductions moved from ds_swizzle (__shfl_xor, LDS
//     pipe, ~12cy + chained latency) to DPP butterflies on the VALU (~2cy);
//     the l-sum tree is DEFERRED entirely (per-lane accumulation, alpha is
//     lane-uniform -> linearity makes one final sum exact). s_setprio(1)
//     wraps MFMA clusters (T5). qp pre-scaled by 0.125, no S scaling.
// ---------------------------------------------------------------------------
__global__ __launch_bounds__(256) void flash_mfma(
    const u16* __restrict__ qp, const u16* __restrict__ kp,
    const u16* __restrict__ vp, float* __restrict__ out)
{
    __shared__ __align__(16) u16 Ks[2][64 * 64];   // row j: 8 chunks, chunk cs at cs^(j&7)
    __shared__ __align__(16) u16 Vt[2][64 * 64];   // row h: 8 j-chunks, chunk cj at cj^(h&7)
    __shared__ __align__(16) u16 Pw[4][16 * 72];

    const int b    = blockIdx.y;
    const int q0   = blockIdx.x * 32;
    const int tid  = threadIdx.x;
    const int lane = tid & 63;
    const int wave = tid >> 6;
    const int wq   = wave & 1;
    const int ks   = wave >> 1;
    const int n    = lane & 15;
    const int g    = lane >> 4;

    const u16* qrow = qp + ((size_t)b * SS + q0 + wq * 16 + n) * HH;
    const short8 qa0 = *(const short8*)(qrow + g * 8);
    const short8 qa1 = *(const short8*)(qrow + 32 + g * 8);

    floatx4 Oa[4];
    #pragma unroll
    for (int ht = 0; ht < 4; ++ht) Oa[ht] = (floatx4){0.f, 0.f, 0.f, 0.f};
    float m_i[4], l_ln[4];   // l_ln: per-lane partial (reduced once at end)
    #pragma unroll
    for (int r = 0; r < 4; ++r) { m_i[r] = -1e30f; l_ln[r] = 0.f; }

    const u16* kb = kp + (size_t)b * SS * HH;
    const u16* vb = vp + (size_t)b * SS * HH;

    // staging indices (tid-only)
    const int jK0 = tid >> 3, jK1 = 32 + (tid >> 3), cs = tid & 7;
    const int jV  = (tid & 15) * 4, hV = (tid >> 4) * 4;

    short8  kr0, kr1;
    ushort4 vr0, vr1, vr2, vr3;

    // ---- prologue: stage tile 0 into buf 0 --------------------------------
    kr0 = *(const short8*)(kb + (size_t)jK0 * HH + cs * 8);
    kr1 = *(const short8*)(kb + (size_t)jK1 * HH + cs * 8);
    vr0 = *(const ushort4*)(vb + (size_t)(jV + 0) * HH + hV);
    vr1 = *(const ushort4*)(vb + (size_t)(jV + 1) * HH + hV);
    vr2 = *(const ushort4*)(vb + (size_t)(jV + 2) * HH + hV);
    vr3 = *(const ushort4*)(vb + (size_t)(jV + 3) * HH + hV);
    {
        *(short8*)&Ks[0][jK0 * 64 + ((cs ^ (jK0 & 7)) << 3)] = kr0;
        *(short8*)&Ks[0][jK1 * 64 + ((cs ^ (jK1 & 7)) << 3)] = kr1;
        const u16* a0 = (const u16*)&vr0; const u16* a1 = (const u16*)&vr1;
        const u16* a2 = (const u16*)&vr2; const u16* a3 = (const u16*)&vr3;
        #pragma unroll
        for (int i = 0; i < 4; ++i) {
            const int h = hV + i;
            ushort4 w; w.x = a0[i]; w.y = a1[i]; w.z = a2[i]; w.w = a3[i];
            *(ushort4*)((char*)&Vt[0][0] + h * 128 + (((jV >> 3) ^ (h & 7)) << 4) + ((jV & 4) << 1)) = w;
        }
    }
    __syncthreads();

    for (int t = 0; t < SS / 64; ++t) {
        const int cur = t & 1;

        // ---- issue next tile's global loads (latency hides under compute) --
        if (t + 1 < SS / 64) {
            const size_t kt = (size_t)(t + 1) * 64;
            kr0 = *(const short8*)(kb + (kt + jK0) * HH + cs * 8);
            kr1 = *(const short8*)(kb + (kt + jK1) * HH + cs * 8);
            vr0 = *(const ushort4*)(vb + (kt + jV + 0) * HH + hV);
            vr1 = *(const ushort4*)(vb + (kt + jV + 1) * HH + hV);
            vr2 = *(const ushort4*)(vb + (kt + jV + 2) * HH + hV);
            vr3 = *(const ushort4*)(vb + (kt + jV + 3) * HH + hV);
        }

        // ---- QK^T: S[16 q][32 keys] (my half) ------------------------------
        floatx4 S[2];
        #pragma unroll
        for (int nt = 0; nt < 2; ++nt) {
            const int j = ks * 32 + nt * 16 + n;
            const short8 kf0 = *(const short8*)&Ks[cur][j * 64 + (((0 + g) ^ (j & 7)) << 3)];
            const short8 kf1 = *(const short8*)&Ks[cur][j * 64 + (((4 + g) ^ (j & 7)) << 3)];
            floatx4 a = (floatx4){0.f, 0.f, 0.f, 0.f};
            __builtin_amdgcn_s_setprio(1);
            a = __builtin_amdgcn_mfma_f32_16x16x32_bf16(qa0, kf0, a, 0, 0, 0);
            a = __builtin_amdgcn_mfma_f32_16x16x32_bf16(qa1, kf1, a, 0, 0, 0);
            __builtin_amdgcn_s_setprio(0);
            S[nt] = a;
        }

        // ---- online softmax (DPP max tree; l deferred to per-lane acc) -----
        float mx[4];
        #pragma unroll
        for (int r = 0; r < 4; ++r)
            mx[r] = red_max16(fmaxf(S[0][r], S[1][r]));

        float alpha[4];
        #pragma unroll
        for (int r = 0; r < 4; ++r) {
            const float Mn = fmaxf(m_i[r], mx[r]);
            alpha[r] = __expf(m_i[r] - Mn);
            m_i[r]   = Mn;
        }
        float p[2][4];
        #pragma unroll
        for (int nt = 0; nt < 2; ++nt)
            #pragma unroll
            for (int r = 0; r < 4; ++r)
                p[nt][r] = __expf(S[nt][r] - m_i[r]);
        #pragma unroll
        for (int r = 0; r < 4; ++r)
            l_ln[r] = l_ln[r] * alpha[r] + (p[0][r] + p[1][r]);
        #pragma unroll
        for (int ht = 0; ht < 4; ++ht)
            #pragma unroll
            for (int r = 0; r < 4; ++r) Oa[ht][r] *= alpha[r];

        // ---- P: C-layout -> LDS -> A-layout (per-wave, no barrier needed) --
        #pragma unroll
        for (int nt = 0; nt < 2; ++nt)
            #pragma unroll
            for (int r = 0; r < 4; ++r)
                Pw[wave][(g * 4 + r) * 72 + nt * 16 + n] = f2bf(p[nt][r]);
        const short8 pa = *(const short8*)&Pw[wave][n * 72 + g * 8];

        // ---- PV: O[16 q][64 h] += P[16 x 32] @ V[32 x 64] ------------------
        __builtin_amdgcn_s_setprio(1);
        #pragma unroll
        for (int ht = 0; ht < 4; ++ht) {
            const int h = ht * 16 + n;
            const short8 vf = *(const short8*)((const char*)&Vt[cur][0] + h * 128 +
                                               ((((ks << 2) + g) ^ (h & 7)) << 4));
            Oa[ht] = __builtin_amdgcn_mfma_f32_16x16x32_bf16(pa, vf, Oa[ht], 0, 0, 0);
        }
        __builtin_amdgcn_s_setprio(0);

        // ---- write next tile into the other buffer -------------------------
        if (t + 1 < SS / 64) {
            const int nx = cur ^ 1;
            *(short8*)&Ks[nx][jK0 * 64 + ((cs ^ (jK0 & 7)) << 3)] = kr0;
            *(short8*)&Ks[nx][jK1 * 64 + ((cs ^ (jK1 & 7)) << 3)] = kr1;
            const u16* a0 = (const u16*)&vr0; const u16* a1 = (const u16*)&vr1;
            const u16* a2 = (const u16*)&vr2; const u16* a3 = (const u16*)&vr3;
            #pragma unroll
            for (int i = 0; i < 4; ++i) {
                const int h = hV + i;
                ushort4 w; w.x = a0[i]; w.y = a1[i]; w.z = a2[i]; w.w = a3[i];
                *(ushort4*)((char*)&Vt[nx][0] + h * 128 + (((jV >> 3) ^ (h & 7)) << 4) + ((jV & 4) << 1)) = w;
            }
        }
        __syncthreads();
    }

    // ---- finalize l: one cross-lane sum (exact by linearity) ---------------
    float l_i[4];
    #pragma unroll
    for (int r = 0; r < 4; ++r) l_i[r] = red_sum16(l_ln[r]);

    // ---- combine the two key-splits via LDS (reuse Ks) ----------------------
    float* Cb = (float*)&Ks[0][0];          // [wq][16][68]
    float* Cm = Cb + 2 * 16 * 68;           // [wq][16]
    float* Cl = Cm + 32;
    if (ks == 1) {
        #pragma unroll
        for (int ht = 0; ht < 4; ++ht)
            #pragma unroll
            for (int r = 0; r < 4; ++r)
                Cb[(wq * 16 + g * 4 + r) * 68 + ht * 16 + n] = Oa[ht][r];
        if (n == 0)
            #pragma unroll
            for (int r = 0; r < 4; ++r) {
                Cm[wq * 16 + g * 4 + r] = m_i[r];
                Cl[wq * 16 + g * 4 + r] = l_i[r];
            }
    }
    __syncthreads();
    if (ks == 0) {
        float a0v[4], a1v[4], linv[4];
        #pragma unroll
        for (int r = 0; r < 4; ++r) {
            const int m = g * 4 + r;
            const float m1 = Cm[wq * 16 + m], l1 = Cl[wq * 16 + m];
            const float M  = fmaxf(m_i[r], m1);
            const float e0 = __expf(m_i[r] - M), e1 = __expf(m1 - M);
            a0v[r] = e0; a1v[r] = e1;
            linv[r] = 1.f / (l_i[r] * e0 + l1 * e1);
        }
        #pragma unroll
        for (int ht = 0; ht < 4; ++ht)
            #pragma unroll
            for (int r = 0; r < 4; ++r) {
                const float o1 = Cb[(wq * 16 + g * 4 + r) * 68 + ht * 16 + n];
                const float v  = (Oa[ht][r] * a0v[r] + o1 * a1v[r]) * linv[r];
                out[((size_t)b * SS + q0 + wq * 16 + g * 4 + r) * HH + ht * 16 + n] = v;
            }
    }
}

// ---------------------------------------------------------------------------
extern "C" void kernel_launch(void* const* d_in, const int* in_sizes, int n_in,
                              void* d_out, int out_size, void* d_ws, size_t ws_size,
                              hipStream_t stream) {
    const float* query = (const float*)d_in[0];
    const float* key   = (const float*)d_in[1];
    const float* value = (const float*)d_in[2];
    const float* Wq    = (const float*)d_in[3];
    const float* bq    = (const float*)d_in[4];
    const float* Wk    = (const float*)d_in[5];
    const float* bk    = (const float*)d_in[6];
    const float* Wv    = (const float*)d_in[7];
    const float* bv    = (const float*)d_in[8];
    float* out = (float*)d_out;

    u16* qp = (u16*)d_ws;                        // 16384 x 64 bf16 each
    u16* kp = qp + (size_t)MM * HH;
    u16* vp = kp + (size_t)MM * HH;
    u16* Wp = vp + (size_t)MM * HH;              // 3 * 256 KB packed W frags

    dim3 wgrid(EE / 64, 3);
    pack_w<<<wgrid, 512, 0, stream>>>(Wq, Wk, Wv, Wp);

    dim3 pgrid(MM / 64, 3);
    proj_mfma<<<pgrid, 256, 0, stream>>>(query, key, value,
                                         Wp,
                                         bq, bk, bv,
                                         qp, kp, vp);

    dim3 agrid(SS / 32, BB);
    flash_mfma<<<agrid, 256, 0, stream>>>(qp, kp, vp, out);
}